// Round 3
// baseline (315.408 us; speedup 1.0000x reference)
//
#include <hip/hip_runtime.h>

#define BATCH 16
#define CH    256
#define NPT   2048
#define DQK   32
#define OTOT  320   // 32 q + 32 k + 256 v
#define EPSB  1e-5f
#define SLOPE 0.2f

typedef __attribute__((ext_vector_type(8))) short bf16x8;
typedef __attribute__((ext_vector_type(4))) float f32x4;

__device__ __forceinline__ unsigned short f2bf(float f) {
    unsigned u = __float_as_uint(f);
    u = (u + 0x7FFFu + ((u >> 16) & 1u)) >> 16;
    return (unsigned short)u;
}
__device__ __forceinline__ float bf2f(unsigned short h) {
    return __uint_as_float(((unsigned)h) << 16);
}

// ---------------------------------------------------------------------------
// Kernel 0: pack weights transposed Wt[c][o] (raw) + bias Bv[o].
// grid 320 x 256.
__global__ __launch_bounds__(256) void prep_kernel(
    const float* __restrict__ qw, const float* __restrict__ qb,
    const float* __restrict__ kw, const float* __restrict__ kb,
    const float* __restrict__ vw, const float* __restrict__ vb,
    float* __restrict__ Wt, float* __restrict__ Bv)
{
    int idx = blockIdx.x * 256 + threadIdx.x;   // < 81920
    int o = idx >> 8, c = idx & 255;
    float w;
    if (o < 32)      w = qw[(size_t)o * CH + c];
    else if (o < 64) w = kw[(size_t)(o - 32) * CH + c];
    else             w = vw[(size_t)(o - 64) * CH + c];
    Wt[(size_t)c * OTOT + o] = w;
    if (idx < OTOT) {
        int oo = idx;
        float bb;
        if (oo < 32)      bb = qb[oo];
        else if (oo < 64) bb = kb[oo - 32];
        else              bb = vb[oo - 64];
        Bv[oo] = bb;
    }
}

// ---------------------------------------------------------------------------
// Kernel 1: conv1x1 (fp32) -> Ybf bf16, fused per-channel stats (atomics).
// grid (2, 20, 16), block 256. Thread tile: 16 o x 4 n.
__global__ __launch_bounds__(256) void conv_kernel(
    const float* __restrict__ x,
    const float* __restrict__ Wt, const float* __restrict__ Bv,
    unsigned short* __restrict__ Ybf,
    float* __restrict__ Sum, float* __restrict__ Sq)
{
    int nh = blockIdx.x;
    int o0 = blockIdx.y * 16;
    int b  = blockIdx.z;
    int n  = nh * 1024 + threadIdx.x * 4;

    const float* xb = x + (size_t)b * CH * NPT + n;

    float4 acc[16];
#pragma unroll
    for (int j = 0; j < 16; ++j) acc[j] = make_float4(0.f, 0.f, 0.f, 0.f);

#pragma unroll 2
    for (int c = 0; c < CH; ++c) {
        float4 xv = *(const float4*)(xb + (size_t)c * NPT);
        const float* wr = Wt + (size_t)c * OTOT + o0;   // wave-uniform row
#pragma unroll
        for (int j = 0; j < 16; ++j) {
            float w = wr[j];
            acc[j].x = fmaf(w, xv.x, acc[j].x);
            acc[j].y = fmaf(w, xv.y, acc[j].y);
            acc[j].z = fmaf(w, xv.z, acc[j].z);
            acc[j].w = fmaf(w, xv.w, acc[j].w);
        }
    }

    unsigned short* yb = Ybf + ((size_t)b * OTOT + o0) * NPT + n;
    int lane = threadIdx.x & 63;
#pragma unroll
    for (int j = 0; j < 16; ++j) {
        float bias = Bv[o0 + j];
        float v0 = acc[j].x + bias, v1 = acc[j].y + bias;
        float v2 = acc[j].z + bias, v3 = acc[j].w + bias;
        ushort4 o4;
        o4.x = f2bf(v0); o4.y = f2bf(v1); o4.z = f2bf(v2); o4.w = f2bf(v3);
        *(ushort4*)(yb + (size_t)j * NPT) = o4;
        float s  = v0 + v1 + v2 + v3;
        float ss = v0*v0 + v1*v1 + v2*v2 + v3*v3;
#pragma unroll
        for (int off = 32; off; off >>= 1) {
            s  += __shfl_down(s, off);
            ss += __shfl_down(ss, off);
        }
        if (lane == 0) {
            atomicAdd(&Sum[o0 + j], s);
            atomicAdd(&Sq[o0 + j], ss);
        }
    }
}

// ---------------------------------------------------------------------------
// Kernel 2: finalize BN affine: A[o], Cc[o].  1 block, 320 threads.
__global__ __launch_bounds__(320) void finalize_kernel(
    const float* __restrict__ Sum, const float* __restrict__ Sq,
    const float* __restrict__ qg, const float* __restrict__ qbe,
    const float* __restrict__ kg, const float* __restrict__ kbe,
    const float* __restrict__ vg, const float* __restrict__ vbe,
    float* __restrict__ A, float* __restrict__ Cc)
{
    int o = threadIdx.x;
    if (o >= OTOT) return;
    const float inv = 1.0f / (BATCH * NPT);
    float mean = Sum[o] * inv;
    float var  = Sq[o] * inv - mean * mean;
    float g, be;
    if (o < 32)      { g = qg[o];      be = qbe[o];      }
    else if (o < 64) { g = kg[o - 32]; be = kbe[o - 32]; }
    else             { g = vg[o - 64]; be = vbe[o - 64]; }
    float a = g * rsqrtf(var + EPSB);
    A[o]  = a;
    Cc[o] = be - mean * a;
}

// ---------------------------------------------------------------------------
// Kernel 3: pack pass — v: affine+LeakyReLU -> Vbf [b][c][n];
//                       q/k: affine + transpose -> QKt [b][n][64].
// grid (32, 16), block 256.
__global__ __launch_bounds__(256) void pack_kernel(
    const unsigned short* __restrict__ Ybf,
    const float* __restrict__ A, const float* __restrict__ Cc,
    unsigned short* __restrict__ QKt, unsigned short* __restrict__ Vbf)
{
    int b = blockIdx.y, n0 = blockIdx.x * 64;
    int tid = threadIdx.x;

    // ---- v part: 256 c x 64 n = 4096 ushort4 units
    for (int e = tid; e < 4096; e += 256) {
        int c = e >> 4, n4 = (e & 15) * 4;
        ushort4 v4 = *(const ushort4*)(Ybf + ((size_t)b * OTOT + 64 + c) * NPT + n0 + n4);
        float a = A[64 + c], cc = Cc[64 + c];
        ushort4 w4;
        unsigned short* pi = (unsigned short*)&v4;
        unsigned short* po = (unsigned short*)&w4;
#pragma unroll
        for (int i = 0; i < 4; ++i) {
            float y = bf2f(pi[i]) * a + cc;
            y = (y > 0.f) ? y : SLOPE * y;
            po[i] = f2bf(y);
        }
        *(ushort4*)(Vbf + ((size_t)b * CH + c) * NPT + n0 + n4) = w4;
    }

    // ---- q/k part: 64 o x 64 n through LDS transpose
    __shared__ unsigned short T[64][72];
    for (int e = tid; e < 1024; e += 256) {
        int o = e >> 4, n4 = (e & 15) * 4;
        ushort4 v4 = *(const ushort4*)(Ybf + ((size_t)b * OTOT + o) * NPT + n0 + n4);
        float a = A[o], cc = Cc[o];
        unsigned short* pi = (unsigned short*)&v4;
#pragma unroll
        for (int i = 0; i < 4; ++i)
            T[n4 + i][o] = f2bf(bf2f(pi[i]) * a + cc);
    }
    __syncthreads();
    for (int e = tid; e < 1024; e += 256) {
        int nn = e >> 4, o4 = (e & 15) * 4;
        ushort4 v4 = *(const ushort4*)&T[nn][o4];
        *(ushort4*)(QKt + ((size_t)b * NPT + n0 + nn) * 64 + o4) = v4;
    }
}

// ---------------------------------------------------------------------------
// Kernel 4: MFMA flash attention, max-free softmax, + residual. (unchanged)
// grid 1024 (XCD-swizzled b,z,n0 decode), block 256 (4 waves).
__global__ __launch_bounds__(256, 4) void attn_kernel(
    const unsigned short* __restrict__ QKt,
    const unsigned short* __restrict__ Vbf,
    const float* __restrict__ x,
    float* __restrict__ out)
{
    int L = blockIdx.x;
    int xcd = L & 7, k = L >> 3;
    int gi = k >> 5, n0i = k & 31;
    int grp = xcd * 4 + gi;           // 0..31
    int b = grp >> 1, z = grp & 1;
    int n0 = n0i * 64;

    int tid = threadIdx.x;
    int w = tid >> 6, lane = tid & 63;
    int quad = lane >> 4, l16 = lane & 15;

    const unsigned short* QK = QKt + (size_t)b * NPT * 64;
    const unsigned short* V  = Vbf + ((size_t)b * CH + z * 128) * NPT;

    __shared__ unsigned short Pbf[64][72];
    __shared__ float rsw[4][64];
    __shared__ float rtot[64];

    bf16x8 qa[4];
#pragma unroll
    for (int nt = 0; nt < 4; ++nt)
        qa[nt] = *(const bf16x8*)(QK + ((size_t)(n0 + nt * 16 + l16)) * 64 + quad * 8);

    f32x4 acc[4][2];
#pragma unroll
    for (int nt = 0; nt < 4; ++nt)
#pragma unroll
        for (int ct = 0; ct < 2; ++ct)
            acc[nt][ct] = (f32x4){0.f, 0.f, 0.f, 0.f};

    float rsum[4][4];
#pragma unroll
    for (int nt = 0; nt < 4; ++nt)
#pragma unroll
        for (int r = 0; r < 4; ++r) rsum[nt][r] = 0.f;

    const f32x4 zero4 = (f32x4){0.f, 0.f, 0.f, 0.f};

    for (int mt = 0; mt < NPT / 64; ++mt) {
        bf16x8 kb = *(const bf16x8*)(QK + ((size_t)(mt * 64 + w * 16 + l16)) * 64 + 32 + quad * 8);

        __syncthreads();   // prev-iter PV reads of Pbf complete

#pragma unroll
        for (int nt = 0; nt < 4; ++nt) {
            f32x4 s = __builtin_amdgcn_mfma_f32_16x16x32_bf16(qa[nt], kb, zero4, 0, 0, 0);
#pragma unroll
            for (int r = 0; r < 4; ++r) {
                float p = __expf(s[r]);         // max-free: |s| << 88
                rsum[nt][r] += p;
                Pbf[nt * 16 + quad * 4 + r][w * 16 + l16] = f2bf(p);
            }
        }
        __syncthreads();   // P visible

#pragma unroll
        for (int ks = 0; ks < 2; ++ks) {
            bf16x8 pa[4];
#pragma unroll
            for (int nt = 0; nt < 4; ++nt)
                pa[nt] = *(const bf16x8*)&Pbf[nt * 16 + l16][ks * 32 + quad * 8];
#pragma unroll
            for (int ct = 0; ct < 2; ++ct) {
                const unsigned short* vp =
                    V + ((size_t)(w * 32 + ct * 16 + l16)) * NPT + mt * 64 + ks * 32 + quad * 8;
                bf16x8 vb = *(const bf16x8*)vp;
#pragma unroll
                for (int nt = 0; nt < 4; ++nt)
                    acc[nt][ct] = __builtin_amdgcn_mfma_f32_16x16x32_bf16(pa[nt], vb, acc[nt][ct], 0, 0, 0);
            }
        }
    }

#pragma unroll
    for (int nt = 0; nt < 4; ++nt)
#pragma unroll
        for (int r = 0; r < 4; ++r) {
            float v = rsum[nt][r];
            v += __shfl_xor(v, 1);
            v += __shfl_xor(v, 2);
            v += __shfl_xor(v, 4);
            v += __shfl_xor(v, 8);
            if (l16 == 0) rsw[w][nt * 16 + quad * 4 + r] = v;
        }
    __syncthreads();
    if (tid < 64)
        rtot[tid] = 1.0f / (rsw[0][tid] + rsw[1][tid] + rsw[2][tid] + rsw[3][tid]);
    __syncthreads();

    float rin[4][4];
#pragma unroll
    for (int nt = 0; nt < 4; ++nt)
#pragma unroll
        for (int r = 0; r < 4; ++r) rin[nt][r] = rtot[nt * 16 + quad * 4 + r];

#pragma unroll
    for (int nt = 0; nt < 4; ++nt)
#pragma unroll
        for (int ct = 0; ct < 2; ++ct) {
            int c = z * 128 + w * 32 + ct * 16 + l16;
            int n = n0 + nt * 16 + quad * 4;
            size_t gi4 = ((size_t)b * CH + c) * NPT + n;
            float4 xv = *(const float4*)(x + gi4);
            float4 o;
            o.x = acc[nt][ct][0] * rin[nt][0] + xv.x;
            o.y = acc[nt][ct][1] * rin[nt][1] + xv.y;
            o.z = acc[nt][ct][2] * rin[nt][2] + xv.z;
            o.w = acc[nt][ct][3] * rin[nt][3] + xv.w;
            *(float4*)(out + gi4) = o;
        }
}

// ---------------------------------------------------------------------------
extern "C" void kernel_launch(void* const* d_in, const int* in_sizes, int n_in,
                              void* d_out, int out_size, void* d_ws, size_t ws_size,
                              hipStream_t stream)
{
    const float* x   = (const float*)d_in[0];
    const float* qw  = (const float*)d_in[1];
    const float* qb  = (const float*)d_in[2];
    const float* qg  = (const float*)d_in[3];
    const float* qbe = (const float*)d_in[4];
    const float* kw  = (const float*)d_in[5];
    const float* kb  = (const float*)d_in[6];
    const float* kg  = (const float*)d_in[7];
    const float* kbe = (const float*)d_in[8];
    const float* vw  = (const float*)d_in[9];
    const float* vb  = (const float*)d_in[10];
    const float* vg  = (const float*)d_in[11];
    const float* vbe = (const float*)d_in[12];
    float* out = (float*)d_out;

    // ws: Ybf (21MB) | QKt (4.2MB; head reused as Wt+Bv before pack) | Vbf (16.8MB)
    //     | Sum,Sq,A,Cc (5KB)
    unsigned short* Ybf = (unsigned short*)d_ws;
    unsigned short* QKt = Ybf + (size_t)BATCH * OTOT * NPT;          // 10,485,760 elems
    unsigned short* Vbf = QKt + (size_t)BATCH * NPT * 64;            // +2,097,152
    float* tail = (float*)(Vbf + (size_t)BATCH * CH * NPT);          // +8,388,608
    float* Sum = tail;
    float* Sq  = tail + OTOT;
    float* A   = tail + 2 * OTOT;
    float* Cc  = tail + 3 * OTOT;
    // overlay: Wt/Bv live in the QKt region, consumed (conv) before pack writes QKt
    float* Wt = (float*)QKt;            // 81,920 floats
    float* Bv = Wt + (size_t)CH * OTOT; // 320 floats

    hipMemsetAsync(Sum, 0, 2 * OTOT * sizeof(float), stream);
    prep_kernel    <<<320, 256, 0, stream>>>(qw, qb, kw, kb, vw, vb, Wt, Bv);
    conv_kernel    <<<dim3(2, OTOT / 16, BATCH), 256, 0, stream>>>(x, Wt, Bv, Ybf, Sum, Sq);
    finalize_kernel<<<1, 320, 0, stream>>>(Sum, Sq, qg, qbe, kg, kbe, vg, vbe, A, Cc);
    pack_kernel    <<<dim3(NPT / 64, BATCH), 256, 0, stream>>>(Ybf, A, Cc, QKt, Vbf);
    attn_kernel    <<<1024, 256, 0, stream>>>(QKt, Vbf, x, out);
}

// Round 4
// 276.162 us; speedup vs baseline: 1.1421x; 1.1421x over previous
//
#include <hip/hip_runtime.h>

#define BATCH 16
#define CH    256
#define NPT   2048
#define DQK   32
#define OTOT  320   // 32 q + 32 k + 256 v
#define EPSB  1e-5f
#define SLOPE 0.2f

typedef __attribute__((ext_vector_type(8))) short bf16x8;
typedef __attribute__((ext_vector_type(4))) float f32x4;

__device__ __forceinline__ unsigned short f2bf(float f) {
    unsigned u = __float_as_uint(f);
    u = (u + 0x7FFFu + ((u >> 16) & 1u)) >> 16;
    return (unsigned short)u;
}
__device__ __forceinline__ float bf2f(unsigned short h) {
    return __uint_as_float(((unsigned)h) << 16);
}

// ---------------------------------------------------------------------------
// Kernel 0: split weights to Whi/Wlo bf16 [o][c] (A-frag layout) + bias Bv[o].
// grid 320 x 256.
__global__ __launch_bounds__(256) void prep_kernel(
    const float* __restrict__ qw, const float* __restrict__ qb,
    const float* __restrict__ kw, const float* __restrict__ kb,
    const float* __restrict__ vw, const float* __restrict__ vb,
    unsigned short* __restrict__ Whi, unsigned short* __restrict__ Wlo,
    float* __restrict__ Bv)
{
    int idx = blockIdx.x * 256 + threadIdx.x;   // < 81920
    int o = idx >> 8, c = idx & 255;
    float w;
    if (o < 32)      w = qw[(size_t)o * CH + c];
    else if (o < 64) w = kw[(size_t)(o - 32) * CH + c];
    else             w = vw[(size_t)(o - 64) * CH + c];
    unsigned short wh = f2bf(w);
    float rem = w - bf2f(wh);
    Whi[idx] = wh;
    Wlo[idx] = f2bf(rem);
    if (idx < OTOT) {
        int oo = idx;
        float bb;
        if (oo < 32)      bb = qb[oo];
        else if (oo < 64) bb = kb[oo - 32];
        else              bb = vb[oo - 64];
        Bv[oo] = bb;
    }
}

// ---------------------------------------------------------------------------
// Kernel 1: conv1x1 as bf16x3 MFMA GEMM (fp32-grade precision).
// Block: 64o x 128n for one b. grid (5, 16, 16), block 256 (waves 2o x 2n).
// Fused: bias, bf16 store, per-channel sum/sumsq atomics.
__global__ __launch_bounds__(256) void conv_kernel(
    const float* __restrict__ x,
    const unsigned short* __restrict__ Whi, const unsigned short* __restrict__ Wlo,
    const float* __restrict__ Bv,
    unsigned short* __restrict__ Ybf,
    float* __restrict__ Sum, float* __restrict__ Sq)
{
    int ob = blockIdx.x * 64;
    int n0 = blockIdx.y * 128;
    int b  = blockIdx.z;
    int tid = threadIdx.x;
    int w = tid >> 6, lane = tid & 63;
    int quad = lane >> 4, l16 = lane & 15;
    int wo = w >> 1, wn = w & 1;

    __shared__ unsigned short Xh[128][40];   // [n_local][c_local], stride 80B (16B-aligned reads)
    __shared__ unsigned short Xl[128][40];

    int nl = tid & 127;       // n_local 0..127
    int ch = tid >> 7;        // c half: covers c_local = ch*16 .. +15
    const float* xb = x + (size_t)b * CH * NPT + n0 + nl;

    f32x4 acc[2][4];
#pragma unroll
    for (int ot = 0; ot < 2; ++ot)
#pragma unroll
        for (int nt = 0; nt < 4; ++nt)
            acc[ot][nt] = (f32x4){0.f, 0.f, 0.f, 0.f};

    // preload k-step 0
    float xv[16];
#pragma unroll
    for (int i = 0; i < 16; ++i)
        xv[i] = xb[(size_t)(ch * 16 + i) * NPT];

    for (int ks = 0; ks < 8; ++ks) {
        __syncthreads();   // prior LDS reads done
        // split + stage (transposed [n][c])
#pragma unroll
        for (int g = 0; g < 4; ++g) {
            ushort4 h4, l4;
            unsigned short* ph = (unsigned short*)&h4;
            unsigned short* pl = (unsigned short*)&l4;
#pragma unroll
            for (int j = 0; j < 4; ++j) {
                float f = xv[g * 4 + j];
                unsigned short h = f2bf(f);
                ph[j] = h;
                pl[j] = f2bf(f - bf2f(h));
            }
            *(ushort4*)&Xh[nl][ch * 16 + g * 4] = h4;
            *(ushort4*)&Xl[nl][ch * 16 + g * 4] = l4;
        }
        __syncthreads();   // tile visible

        // prefetch next k-step while MFMA runs
        if (ks < 7) {
#pragma unroll
            for (int i = 0; i < 16; ++i)
                xv[i] = xb[(size_t)((ks + 1) * 32 + ch * 16 + i) * NPT];
        }

        // A fragments from global (L2/L3-resident, frag-layout exact)
        bf16x8 ah[2], al[2];
#pragma unroll
        for (int ot = 0; ot < 2; ++ot) {
            size_t orow = (size_t)(ob + wo * 32 + ot * 16 + l16) * 256 + ks * 32 + quad * 8;
            ah[ot] = *(const bf16x8*)(Whi + orow);
            al[ot] = *(const bf16x8*)(Wlo + orow);
        }
#pragma unroll
        for (int nt = 0; nt < 4; ++nt) {
            int nr = wn * 64 + nt * 16 + l16;
            bf16x8 bh = *(const bf16x8*)&Xh[nr][quad * 8];
            bf16x8 bl = *(const bf16x8*)&Xl[nr][quad * 8];
#pragma unroll
            for (int ot = 0; ot < 2; ++ot) {
                acc[ot][nt] = __builtin_amdgcn_mfma_f32_16x16x32_bf16(ah[ot], bh, acc[ot][nt], 0, 0, 0);
                acc[ot][nt] = __builtin_amdgcn_mfma_f32_16x16x32_bf16(ah[ot], bl, acc[ot][nt], 0, 0, 0);
                acc[ot][nt] = __builtin_amdgcn_mfma_f32_16x16x32_bf16(al[ot], bh, acc[ot][nt], 0, 0, 0);
            }
        }
    }

    // epilogue: bias, store bf16, per-o stats
#pragma unroll
    for (int ot = 0; ot < 2; ++ot) {
        int obase = ob + wo * 32 + ot * 16 + quad * 4;
        float bias[4], sv[4], sq[4];
#pragma unroll
        for (int r = 0; r < 4; ++r) {
            bias[r] = Bv[obase + r];
            sv[r] = 0.f; sq[r] = 0.f;
        }
#pragma unroll
        for (int nt = 0; nt < 4; ++nt) {
            int n = n0 + wn * 64 + nt * 16 + l16;
#pragma unroll
            for (int r = 0; r < 4; ++r) {
                float v = acc[ot][nt][r] + bias[r];
                Ybf[((size_t)b * OTOT + obase + r) * NPT + n] = f2bf(v);
                sv[r] += v; sq[r] += v * v;
            }
        }
#pragma unroll
        for (int r = 0; r < 4; ++r) {
            float a = sv[r], q = sq[r];
            a += __shfl_xor(a, 1); q += __shfl_xor(q, 1);
            a += __shfl_xor(a, 2); q += __shfl_xor(q, 2);
            a += __shfl_xor(a, 4); q += __shfl_xor(q, 4);
            a += __shfl_xor(a, 8); q += __shfl_xor(q, 8);
            if (l16 == 0) {
                atomicAdd(&Sum[obase + r], a);
                atomicAdd(&Sq[obase + r], q);
            }
        }
    }
}

// ---------------------------------------------------------------------------
// Kernel 2: finalize BN affine: A[o], Cc[o].  1 block, 320 threads.
__global__ __launch_bounds__(320) void finalize_kernel(
    const float* __restrict__ Sum, const float* __restrict__ Sq,
    const float* __restrict__ qg, const float* __restrict__ qbe,
    const float* __restrict__ kg, const float* __restrict__ kbe,
    const float* __restrict__ vg, const float* __restrict__ vbe,
    float* __restrict__ A, float* __restrict__ Cc)
{
    int o = threadIdx.x;
    if (o >= OTOT) return;
    const float inv = 1.0f / (BATCH * NPT);
    float mean = Sum[o] * inv;
    float var  = Sq[o] * inv - mean * mean;
    float g, be;
    if (o < 32)      { g = qg[o];      be = qbe[o];      }
    else if (o < 64) { g = kg[o - 32]; be = kbe[o - 32]; }
    else             { g = vg[o - 64]; be = vbe[o - 64]; }
    float a = g * rsqrtf(var + EPSB);
    A[o]  = a;
    Cc[o] = be - mean * a;
}

// ---------------------------------------------------------------------------
// Kernel 3: pack pass — v: affine+LeakyReLU -> Vbf [b][c][n];
//                       q/k: affine + transpose -> QKt [b][n][64].
// grid (32, 16), block 256.
__global__ __launch_bounds__(256) void pack_kernel(
    const unsigned short* __restrict__ Ybf,
    const float* __restrict__ A, const float* __restrict__ Cc,
    unsigned short* __restrict__ QKt, unsigned short* __restrict__ Vbf)
{
    int b = blockIdx.y, n0 = blockIdx.x * 64;
    int tid = threadIdx.x;

    // ---- v part: 256 c x 64 n = 4096 ushort4 units
    for (int e = tid; e < 4096; e += 256) {
        int c = e >> 4, n4 = (e & 15) * 4;
        ushort4 v4 = *(const ushort4*)(Ybf + ((size_t)b * OTOT + 64 + c) * NPT + n0 + n4);
        float a = A[64 + c], cc = Cc[64 + c];
        ushort4 w4;
        unsigned short* pi = (unsigned short*)&v4;
        unsigned short* po = (unsigned short*)&w4;
#pragma unroll
        for (int i = 0; i < 4; ++i) {
            float y = bf2f(pi[i]) * a + cc;
            y = (y > 0.f) ? y : SLOPE * y;
            po[i] = f2bf(y);
        }
        *(ushort4*)(Vbf + ((size_t)b * CH + c) * NPT + n0 + n4) = w4;
    }

    // ---- q/k part: 64 o x 64 n through LDS transpose
    __shared__ unsigned short T[64][72];
    for (int e = tid; e < 1024; e += 256) {
        int o = e >> 4, n4 = (e & 15) * 4;
        ushort4 v4 = *(const ushort4*)(Ybf + ((size_t)b * OTOT + o) * NPT + n0 + n4);
        float a = A[o], cc = Cc[o];
        unsigned short* pi = (unsigned short*)&v4;
#pragma unroll
        for (int i = 0; i < 4; ++i)
            T[n4 + i][o] = f2bf(bf2f(pi[i]) * a + cc);
    }
    __syncthreads();
    for (int e = tid; e < 1024; e += 256) {
        int nn = e >> 4, o4 = (e & 15) * 4;
        ushort4 v4 = *(const ushort4*)&T[nn][o4];
        *(ushort4*)(QKt + ((size_t)b * NPT + n0 + nn) * 64 + o4) = v4;
    }
}

// ---------------------------------------------------------------------------
// Kernel 4: MFMA flash attention, max-free softmax, + residual. (unchanged)
// grid 1024 (XCD-swizzled b,z,n0 decode), block 256 (4 waves).
__global__ __launch_bounds__(256, 4) void attn_kernel(
    const unsigned short* __restrict__ QKt,
    const unsigned short* __restrict__ Vbf,
    const float* __restrict__ x,
    float* __restrict__ out)
{
    int L = blockIdx.x;
    int xcd = L & 7, k = L >> 3;
    int gi = k >> 5, n0i = k & 31;
    int grp = xcd * 4 + gi;           // 0..31
    int b = grp >> 1, z = grp & 1;
    int n0 = n0i * 64;

    int tid = threadIdx.x;
    int w = tid >> 6, lane = tid & 63;
    int quad = lane >> 4, l16 = lane & 15;

    const unsigned short* QK = QKt + (size_t)b * NPT * 64;
    const unsigned short* V  = Vbf + ((size_t)b * CH + z * 128) * NPT;

    __shared__ unsigned short Pbf[64][72];
    __shared__ float rsw[4][64];
    __shared__ float rtot[64];

    bf16x8 qa[4];
#pragma unroll
    for (int nt = 0; nt < 4; ++nt)
        qa[nt] = *(const bf16x8*)(QK + ((size_t)(n0 + nt * 16 + l16)) * 64 + quad * 8);

    f32x4 acc[4][2];
#pragma unroll
    for (int nt = 0; nt < 4; ++nt)
#pragma unroll
        for (int ct = 0; ct < 2; ++ct)
            acc[nt][ct] = (f32x4){0.f, 0.f, 0.f, 0.f};

    float rsum[4][4];
#pragma unroll
    for (int nt = 0; nt < 4; ++nt)
#pragma unroll
        for (int r = 0; r < 4; ++r) rsum[nt][r] = 0.f;

    const f32x4 zero4 = (f32x4){0.f, 0.f, 0.f, 0.f};

    for (int mt = 0; mt < NPT / 64; ++mt) {
        bf16x8 kb = *(const bf16x8*)(QK + ((size_t)(mt * 64 + w * 16 + l16)) * 64 + 32 + quad * 8);

        __syncthreads();   // prev-iter PV reads of Pbf complete

#pragma unroll
        for (int nt = 0; nt < 4; ++nt) {
            f32x4 s = __builtin_amdgcn_mfma_f32_16x16x32_bf16(qa[nt], kb, zero4, 0, 0, 0);
#pragma unroll
            for (int r = 0; r < 4; ++r) {
                float p = __expf(s[r]);         // max-free: |s| << 88
                rsum[nt][r] += p;
                Pbf[nt * 16 + quad * 4 + r][w * 16 + l16] = f2bf(p);
            }
        }
        __syncthreads();   // P visible

#pragma unroll
        for (int ks = 0; ks < 2; ++ks) {
            bf16x8 pa[4];
#pragma unroll
            for (int nt = 0; nt < 4; ++nt)
                pa[nt] = *(const bf16x8*)&Pbf[nt * 16 + l16][ks * 32 + quad * 8];
#pragma unroll
            for (int ct = 0; ct < 2; ++ct) {
                const unsigned short* vp =
                    V + ((size_t)(w * 32 + ct * 16 + l16)) * NPT + mt * 64 + ks * 32 + quad * 8;
                bf16x8 vb = *(const bf16x8*)vp;
#pragma unroll
                for (int nt = 0; nt < 4; ++nt)
                    acc[nt][ct] = __builtin_amdgcn_mfma_f32_16x16x32_bf16(pa[nt], vb, acc[nt][ct], 0, 0, 0);
            }
        }
    }

#pragma unroll
    for (int nt = 0; nt < 4; ++nt)
#pragma unroll
        for (int r = 0; r < 4; ++r) {
            float v = rsum[nt][r];
            v += __shfl_xor(v, 1);
            v += __shfl_xor(v, 2);
            v += __shfl_xor(v, 4);
            v += __shfl_xor(v, 8);
            if (l16 == 0) rsw[w][nt * 16 + quad * 4 + r] = v;
        }
    __syncthreads();
    if (tid < 64)
        rtot[tid] = 1.0f / (rsw[0][tid] + rsw[1][tid] + rsw[2][tid] + rsw[3][tid]);
    __syncthreads();

    float rin[4][4];
#pragma unroll
    for (int nt = 0; nt < 4; ++nt)
#pragma unroll
        for (int r = 0; r < 4; ++r) rin[nt][r] = rtot[nt * 16 + quad * 4 + r];

#pragma unroll
    for (int nt = 0; nt < 4; ++nt)
#pragma unroll
        for (int ct = 0; ct < 2; ++ct) {
            int c = z * 128 + w * 32 + ct * 16 + l16;
            int n = n0 + nt * 16 + quad * 4;
            size_t gi4 = ((size_t)b * CH + c) * NPT + n;
            float4 xv = *(const float4*)(x + gi4);
            float4 o;
            o.x = acc[nt][ct][0] * rin[nt][0] + xv.x;
            o.y = acc[nt][ct][1] * rin[nt][1] + xv.y;
            o.z = acc[nt][ct][2] * rin[nt][2] + xv.z;
            o.w = acc[nt][ct][3] * rin[nt][3] + xv.w;
            *(float4*)(out + gi4) = o;
        }
}

// ---------------------------------------------------------------------------
extern "C" void kernel_launch(void* const* d_in, const int* in_sizes, int n_in,
                              void* d_out, int out_size, void* d_ws, size_t ws_size,
                              hipStream_t stream)
{
    const float* x   = (const float*)d_in[0];
    const float* qw  = (const float*)d_in[1];
    const float* qb  = (const float*)d_in[2];
    const float* qg  = (const float*)d_in[3];
    const float* qbe = (const float*)d_in[4];
    const float* kw  = (const float*)d_in[5];
    const float* kb  = (const float*)d_in[6];
    const float* kg  = (const float*)d_in[7];
    const float* kbe = (const float*)d_in[8];
    const float* vw  = (const float*)d_in[9];
    const float* vb  = (const float*)d_in[10];
    const float* vg  = (const float*)d_in[11];
    const float* vbe = (const float*)d_in[12];
    float* out = (float*)d_out;

    // ws: Ybf (21MB) | QKt (4.2MB; head reused as Whi/Wlo/Bv before pack) | Vbf (16.8MB)
    //     | Sum,Sq,A,Cc (5KB)
    unsigned short* Ybf = (unsigned short*)d_ws;
    unsigned short* QKt = Ybf + (size_t)BATCH * OTOT * NPT;          // 10,485,760 elems
    unsigned short* Vbf = QKt + (size_t)BATCH * NPT * 64;            // +2,097,152
    float* tail = (float*)(Vbf + (size_t)BATCH * CH * NPT);          // +8,388,608
    float* Sum = tail;
    float* Sq  = tail + OTOT;
    float* A   = tail + 2 * OTOT;
    float* Cc  = tail + 3 * OTOT;
    // overlay: Whi/Wlo/Bv live in QKt region, consumed (conv) before pack writes QKt
    unsigned short* Whi = QKt;                         // 81,920 ushorts
    unsigned short* Wlo = Whi + (size_t)CH * OTOT;     // 81,920 ushorts
    float* Bv = (float*)(Wlo + (size_t)CH * OTOT);     // 320 floats

    hipMemsetAsync(Sum, 0, 2 * OTOT * sizeof(float), stream);
    prep_kernel    <<<320, 256, 0, stream>>>(qw, qb, kw, kb, vw, vb, Whi, Wlo, Bv);
    conv_kernel    <<<dim3(5, 16, 16), 256, 0, stream>>>(x, Whi, Wlo, Bv, Ybf, Sum, Sq);
    finalize_kernel<<<1, 320, 0, stream>>>(Sum, Sq, qg, qbe, kg, kbe, vg, vbe, A, Cc);
    pack_kernel    <<<dim3(NPT / 64, BATCH), 256, 0, stream>>>(Ybf, A, Cc, QKt, Vbf);
    attn_kernel    <<<1024, 256, 0, stream>>>(QKt, Vbf, x, out);
}